// Round 1
// baseline (16197.964 us; speedup 1.0000x reference)
//
#include <hip/hip_runtime.h>
#include <hip/hip_bf16.h>

#define DT 0.1f
#define TAU_HP 12.3f
#define TAU_LP 2.3f

// ---------------------------------------------------------------------------
// Workspace layout (floats):
//   v      [n_neurons]
//   syn    [n_neurons]
//   tm1_f  [n_tm1]
//   tm1_v  [n_tm1]
// Total: (2*200000 + 2*25000)*4 = 1.8 MB
// ---------------------------------------------------------------------------

__global__ void init_kernel(float* __restrict__ v,
                            float* __restrict__ tm1_f,
                            float* __restrict__ tm1_v,
                            int n_neurons, int n_tm1) {
    int i = blockIdx.x * blockDim.x + threadIdx.x;
    if (i < n_neurons) v[i] = 0.0f;
    if (i < n_tm1) { tm1_f[i] = 0.0f; tm1_v[i] = 0.0f; }
}

// Fused: (a) apply previous step's dv for i >= n_tm1 (do_update=1),
//        (b) zero syn for this step's scatter,
//        (c) Tm1 filter update + v[i] = old tm1_v for i < n_tm1.
__global__ void neuron_kernel(float* __restrict__ v,
                              float* __restrict__ syn,
                              float* __restrict__ tm1_f,
                              float* __restrict__ tm1_v,
                              const float* __restrict__ x,      // tm1_input[t]
                              const float* __restrict__ tau,
                              const float* __restrict__ vrest,
                              int n_neurons, int n_tm1, int do_update) {
    int i = blockIdx.x * blockDim.x + threadIdx.x;
    if (i >= n_neurons) return;

    if (do_update && i >= n_tm1) {
        float vi = v[i];
        float dv = (-vi + syn[i] + vrest[i]) / tau[i];
        v[i] = vi + DT * dv;
    }
    syn[i] = 0.0f;

    if (i < n_tm1) {
        float f  = tm1_f[i];
        float tv = tm1_v[i];
        float xi = x[i];
        float hp = xi - f;
        tm1_f[i] = f + DT * (xi - f) / TAU_HP;
        v[i] = tv;                                // old tm1_v into v before recurrence
        float rect = fmaxf(hp, 0.0f);
        tm1_v[i] = tv + DT * (rect - tv) / TAU_LP;
    }
}

// 4 edges per thread, vectorized loads.
__global__ void edge_kernel(const int4* __restrict__ src4,
                            const int4* __restrict__ tgt4,
                            const float4* __restrict__ w4,
                            const float* __restrict__ v,
                            float* __restrict__ syn,
                            int n_edges4) {
    int i = blockIdx.x * blockDim.x + threadIdx.x;
    if (i >= n_edges4) return;
    int4   s = src4[i];
    int4   t = tgt4[i];
    float4 w = w4[i];
    float c0 = fmaxf(v[s.x], 0.0f) * w.x;
    float c1 = fmaxf(v[s.y], 0.0f) * w.y;
    float c2 = fmaxf(v[s.z], 0.0f) * w.z;
    float c3 = fmaxf(v[s.w], 0.0f) * w.w;
    atomicAdd(&syn[t.x], c0);
    atomicAdd(&syn[t.y], c1);
    atomicAdd(&syn[t.z], c2);
    atomicAdd(&syn[t.w], c3);
}

// Apply the last step's dv and emit final v to d_out.
__global__ void final_kernel(const float* __restrict__ v,
                             const float* __restrict__ syn,
                             const float* __restrict__ tau,
                             const float* __restrict__ vrest,
                             float* __restrict__ out,
                             int n_neurons, int n_tm1) {
    int i = blockIdx.x * blockDim.x + threadIdx.x;
    if (i >= n_neurons) return;
    float vi = v[i];
    if (i >= n_tm1) {
        vi = vi + DT * ((-vi + syn[i] + vrest[i]) / tau[i]);
    }
    out[i] = vi;
}

extern "C" void kernel_launch(void* const* d_in, const int* in_sizes, int n_in,
                              void* d_out, int out_size, void* d_ws, size_t ws_size,
                              hipStream_t stream) {
    const float* tm1_input  = (const float*)d_in[0];   // [steps * n_tm1]
    const float* weights    = (const float*)d_in[1];   // [n_edges]
    const float* tau        = (const float*)d_in[2];   // [n_neurons]
    const float* vrest      = (const float*)d_in[3];   // [n_neurons]
    const int*   source_idx = (const int*)d_in[4];     // [n_edges]
    const int*   target_idx = (const int*)d_in[5];     // [n_edges]
    // d_in[6] is n_tm1 scalar on device; shapes are fixed by the problem.

    const int n_edges   = in_sizes[1];
    const int n_neurons = in_sizes[2];
    const int n_tm1     = 25000;
    const int steps     = in_sizes[0] / n_tm1;

    float* ws    = (float*)d_ws;
    float* v     = ws;
    float* syn   = ws + n_neurons;
    float* tm1_f = ws + 2 * n_neurons;
    float* tm1_v = ws + 2 * n_neurons + n_tm1;

    float* out = (float*)d_out;

    const int B = 256;
    const int gridN = (n_neurons + B - 1) / B;
    const int n_edges4 = n_edges / 4;
    const int gridE = (n_edges4 + B - 1) / B;

    init_kernel<<<gridN, B, 0, stream>>>(v, tm1_f, tm1_v, n_neurons, n_tm1);

    for (int t = 0; t < steps; ++t) {
        neuron_kernel<<<gridN, B, 0, stream>>>(
            v, syn, tm1_f, tm1_v,
            tm1_input + (size_t)t * n_tm1,
            tau, vrest, n_neurons, n_tm1, t > 0 ? 1 : 0);
        edge_kernel<<<gridE, B, 0, stream>>>(
            (const int4*)source_idx, (const int4*)target_idx,
            (const float4*)weights, v, syn, n_edges4);
    }

    final_kernel<<<gridN, B, 0, stream>>>(v, syn, tau, vrest, out, n_neurons, n_tm1);
}

// Round 2
// 5249.888 us; speedup vs baseline: 3.0854x; 3.0854x over previous
//
#include <hip/hip_runtime.h>
#include <hip/hip_bf16.h>

#define DT 0.1f
#define TAU_HP 12.3f
#define TAU_LP 2.3f
#define SCAN_B 1024

// ---------------------------------------------------------------------------
// Strategy: atomics were the bottleneck (200 MB HBM write-through per edge
// dispatch). Build CSR-by-target once per launch, then per-step edge pass is
// an atomic-free per-row gather-sum over interleaved (src, w) int2 records.
// ---------------------------------------------------------------------------

__global__ void init_kernel(float* __restrict__ v,
                            float* __restrict__ tm1_f,
                            float* __restrict__ tm1_v,
                            int* __restrict__ counts,
                            int n_neurons, int n_tm1) {
    int i = blockIdx.x * blockDim.x + threadIdx.x;
    if (i < n_neurons) { v[i] = 0.0f; counts[i] = 0; }
    if (i < n_tm1) { tm1_f[i] = 0.0f; tm1_v[i] = 0.0f; }
}

// --- CSR build ---------------------------------------------------------------

__global__ void hist_kernel(const int4* __restrict__ tgt4, int* __restrict__ counts,
                            int n_edges4) {
    int i = blockIdx.x * blockDim.x + threadIdx.x;
    if (i >= n_edges4) return;
    int4 t = tgt4[i];
    atomicAdd(&counts[t.x], 1);
    atomicAdd(&counts[t.y], 1);
    atomicAdd(&counts[t.z], 1);
    atomicAdd(&counts[t.w], 1);
}

// Per-block exclusive scan (Hillis-Steele in LDS), block sums out.
__global__ void scan1_kernel(const int* __restrict__ in, int* __restrict__ out,
                             int* __restrict__ bsums, int n) {
    __shared__ int s[SCAN_B];
    int gid = blockIdx.x * SCAN_B + threadIdx.x;
    int x = (gid < n) ? in[gid] : 0;
    s[threadIdx.x] = x;
    __syncthreads();
    for (int off = 1; off < SCAN_B; off <<= 1) {
        int t = (threadIdx.x >= off) ? s[threadIdx.x - off] : 0;
        __syncthreads();
        s[threadIdx.x] += t;
        __syncthreads();
    }
    if (gid < n) out[gid] = s[threadIdx.x] - x;       // exclusive
    if (threadIdx.x == SCAN_B - 1) bsums[blockIdx.x] = s[SCAN_B - 1];
}

// Single-block exclusive scan of block sums (nb <= 1024).
__global__ void scan2_kernel(int* __restrict__ bsums, int nb) {
    __shared__ int s[SCAN_B];
    int x = (threadIdx.x < nb) ? bsums[threadIdx.x] : 0;
    s[threadIdx.x] = x;
    __syncthreads();
    for (int off = 1; off < SCAN_B; off <<= 1) {
        int t = (threadIdx.x >= off) ? s[threadIdx.x - off] : 0;
        __syncthreads();
        s[threadIdx.x] += t;
        __syncthreads();
    }
    if (threadIdx.x < nb) bsums[threadIdx.x] = s[threadIdx.x] - x;
}

// Add scanned block sums; emit row_start and cursor copies.
__global__ void scan3_kernel(int* __restrict__ row_start, int* __restrict__ cursor,
                             const int* __restrict__ bsums, int n, int n_edges) {
    int gid = blockIdx.x * blockDim.x + threadIdx.x;
    if (gid < n) {
        int vv = row_start[gid] + bsums[gid / SCAN_B];
        row_start[gid] = vv;
        cursor[gid] = vv;
    }
    if (gid == n) row_start[n] = n_edges;
}

// Scatter edges into CSR order: (src, weight-bits) interleaved.
__global__ void scatter_kernel(const int* __restrict__ src, const int* __restrict__ tgt,
                               const float* __restrict__ w, int* __restrict__ cursor,
                               int2* __restrict__ edges, int n_edges) {
    int i = blockIdx.x * blockDim.x + threadIdx.x;
    if (i >= n_edges) return;
    int t = tgt[i];
    int pos = atomicAdd(&cursor[t], 1);
    edges[pos] = make_int2(src[i], __float_as_int(w[i]));
}

// --- Per-step kernels --------------------------------------------------------

// Apply previous step's dv (i >= n_tm1, when do_update), Tm1 filter update +
// v[i] = old tm1_v for i < n_tm1. syn is fully overwritten by gather_kernel.
__global__ void neuron_kernel(float* __restrict__ v,
                              const float* __restrict__ syn,
                              float* __restrict__ tm1_f,
                              float* __restrict__ tm1_v,
                              const float* __restrict__ x,
                              const float* __restrict__ tau,
                              const float* __restrict__ vrest,
                              int n_neurons, int n_tm1, int do_update) {
    int i = blockIdx.x * blockDim.x + threadIdx.x;
    if (i >= n_neurons) return;

    if (i < n_tm1) {
        float f  = tm1_f[i];
        float tv = tm1_v[i];
        float xi = x[i];
        float hp = xi - f;
        tm1_f[i] = f + DT * (xi - f) / TAU_HP;
        v[i] = tv;                                // old tm1_v into v before recurrence
        float rect = fmaxf(hp, 0.0f);
        tm1_v[i] = tv + DT * (rect - tv) / TAU_LP;
    } else if (do_update) {
        float vi = v[i];
        float dv = (-vi + syn[i] + vrest[i]) / tau[i];
        v[i] = vi + DT * dv;
    }
}

// Atomic-free CSR gather: syn[i] = sum over incoming edges of relu(v[src])*w.
__global__ void gather_kernel(const int* __restrict__ row_start,
                              const int2* __restrict__ edges,
                              const float* __restrict__ v,
                              float* __restrict__ syn, int n) {
    int i = blockIdx.x * blockDim.x + threadIdx.x;
    if (i >= n) return;
    int s = row_start[i];
    int e = row_start[i + 1];
    float sum = 0.0f;
    for (int j = s; j < e; ++j) {
        int2 ed = edges[j];
        sum += fmaxf(v[ed.x], 0.0f) * __int_as_float(ed.y);
    }
    syn[i] = sum;
}

// Apply last step's dv and emit final v.
__global__ void final_kernel(const float* __restrict__ v,
                             const float* __restrict__ syn,
                             const float* __restrict__ tau,
                             const float* __restrict__ vrest,
                             float* __restrict__ out,
                             int n_neurons, int n_tm1) {
    int i = blockIdx.x * blockDim.x + threadIdx.x;
    if (i >= n_neurons) return;
    float vi = v[i];
    if (i >= n_tm1) {
        vi = vi + DT * ((-vi + syn[i] + vrest[i]) / tau[i]);
    }
    out[i] = vi;
}

extern "C" void kernel_launch(void* const* d_in, const int* in_sizes, int n_in,
                              void* d_out, int out_size, void* d_ws, size_t ws_size,
                              hipStream_t stream) {
    const float* tm1_input  = (const float*)d_in[0];
    const float* weights    = (const float*)d_in[1];
    const float* tau        = (const float*)d_in[2];
    const float* vrest      = (const float*)d_in[3];
    const int*   source_idx = (const int*)d_in[4];
    const int*   target_idx = (const int*)d_in[5];

    const int n_edges   = in_sizes[1];
    const int n_neurons = in_sizes[2];
    const int n_tm1     = 25000;
    const int steps     = in_sizes[0] / n_tm1;

    // Workspace carve-up (element offsets in 4-byte units, int2 8B-aligned).
    size_t off = 0;
    auto alloc_f = [&](size_t n) { size_t o = off; off += n; return o; };
    auto align2  = [&]() { if (off & 1) ++off; };

    float* ws_f = (float*)d_ws;
    int*   ws_i = (int*)d_ws;

    float* v         = ws_f + alloc_f(n_neurons);
    float* syn       = ws_f + alloc_f(n_neurons);
    float* tm1_f     = ws_f + alloc_f(n_tm1);
    float* tm1_v     = ws_f + alloc_f(n_tm1);
    int*   counts    = ws_i + alloc_f(n_neurons);
    int*   row_start = ws_i + alloc_f(n_neurons + 1);
    int*   cursor    = ws_i + alloc_f(n_neurons);
    int*   bsums     = ws_i + alloc_f(SCAN_B);
    align2();
    int2*  edges     = (int2*)(ws_i + alloc_f((size_t)n_edges * 2));
    (void)ws_size;

    float* out = (float*)d_out;

    const int B = 256;
    const int gridN  = (n_neurons + B - 1) / B;
    const int gridN1 = (n_neurons + 1 + B - 1) / B;
    const int gridE  = (n_edges + B - 1) / B;
    const int n_edges4 = n_edges / 4;
    const int gridE4 = (n_edges4 + B - 1) / B;
    const int nScanBlocks = (n_neurons + SCAN_B - 1) / SCAN_B;

    // --- one-time (per launch) CSR build ---
    init_kernel<<<gridN, B, 0, stream>>>(v, tm1_f, tm1_v, counts, n_neurons, n_tm1);
    hist_kernel<<<gridE4, B, 0, stream>>>((const int4*)target_idx, counts, n_edges4);
    scan1_kernel<<<nScanBlocks, SCAN_B, 0, stream>>>(counts, row_start, bsums, n_neurons);
    scan2_kernel<<<1, SCAN_B, 0, stream>>>(bsums, nScanBlocks);
    scan3_kernel<<<gridN1, B, 0, stream>>>(row_start, cursor, bsums, n_neurons, n_edges);
    scatter_kernel<<<gridE, B, 0, stream>>>(source_idx, target_idx, weights, cursor,
                                            edges, n_edges);

    // --- 50 steps, atomic-free ---
    for (int t = 0; t < steps; ++t) {
        neuron_kernel<<<gridN, B, 0, stream>>>(
            v, syn, tm1_f, tm1_v,
            tm1_input + (size_t)t * n_tm1,
            tau, vrest, n_neurons, n_tm1, t > 0 ? 1 : 0);
        gather_kernel<<<gridN, B, 0, stream>>>(row_start, edges, v, syn, n_neurons);
    }

    final_kernel<<<gridN, B, 0, stream>>>(v, syn, tau, vrest, out, n_neurons, n_tm1);
}

// Round 3
// 2661.017 us; speedup vs baseline: 6.0871x; 1.9729x over previous
//
#include <hip/hip_runtime.h>
#include <hip/hip_bf16.h>

#define DT 0.1f
#define TAU_HP 12.3f
#define TAU_LP 2.3f
#define SCAN_B 1024

// ---------------------------------------------------------------------------
// R1: atomics removed via CSR-by-target (200 MB/step HBM write-through gone).
// R2: gather was latency-bound (1 thread/row, serial 8B loads, uncoalesced).
//     -> CSR-vector: 16 lanes per row, coalesced 128B reads, shfl reduction.
// ---------------------------------------------------------------------------

__global__ void init_kernel(float* __restrict__ v,
                            float* __restrict__ tm1_f,
                            float* __restrict__ tm1_v,
                            int* __restrict__ counts,
                            int n_neurons, int n_tm1) {
    int i = blockIdx.x * blockDim.x + threadIdx.x;
    if (i < n_neurons) { v[i] = 0.0f; counts[i] = 0; }
    if (i < n_tm1) { tm1_f[i] = 0.0f; tm1_v[i] = 0.0f; }
}

// --- CSR build ---------------------------------------------------------------

__global__ void hist_kernel(const int4* __restrict__ tgt4, int* __restrict__ counts,
                            int n_edges4) {
    int i = blockIdx.x * blockDim.x + threadIdx.x;
    if (i >= n_edges4) return;
    int4 t = tgt4[i];
    atomicAdd(&counts[t.x], 1);
    atomicAdd(&counts[t.y], 1);
    atomicAdd(&counts[t.z], 1);
    atomicAdd(&counts[t.w], 1);
}

// Per-block exclusive scan (Hillis-Steele in LDS), block sums out.
__global__ void scan1_kernel(const int* __restrict__ in, int* __restrict__ out,
                             int* __restrict__ bsums, int n) {
    __shared__ int s[SCAN_B];
    int gid = blockIdx.x * SCAN_B + threadIdx.x;
    int x = (gid < n) ? in[gid] : 0;
    s[threadIdx.x] = x;
    __syncthreads();
    for (int off = 1; off < SCAN_B; off <<= 1) {
        int t = (threadIdx.x >= off) ? s[threadIdx.x - off] : 0;
        __syncthreads();
        s[threadIdx.x] += t;
        __syncthreads();
    }
    if (gid < n) out[gid] = s[threadIdx.x] - x;       // exclusive
    if (threadIdx.x == SCAN_B - 1) bsums[blockIdx.x] = s[SCAN_B - 1];
}

// Single-block exclusive scan of block sums (nb <= 1024).
__global__ void scan2_kernel(int* __restrict__ bsums, int nb) {
    __shared__ int s[SCAN_B];
    int x = (threadIdx.x < nb) ? bsums[threadIdx.x] : 0;
    s[threadIdx.x] = x;
    __syncthreads();
    for (int off = 1; off < SCAN_B; off <<= 1) {
        int t = (threadIdx.x >= off) ? s[threadIdx.x - off] : 0;
        __syncthreads();
        s[threadIdx.x] += t;
        __syncthreads();
    }
    if (threadIdx.x < nb) bsums[threadIdx.x] = s[threadIdx.x] - x;
}

// Add scanned block sums; emit row_start and cursor copies.
__global__ void scan3_kernel(int* __restrict__ row_start, int* __restrict__ cursor,
                             const int* __restrict__ bsums, int n, int n_edges) {
    int gid = blockIdx.x * blockDim.x + threadIdx.x;
    if (gid < n) {
        int vv = row_start[gid] + bsums[gid / SCAN_B];
        row_start[gid] = vv;
        cursor[gid] = vv;
    }
    if (gid == n) row_start[n] = n_edges;
}

// Scatter edges into CSR order: (src, weight-bits) interleaved.
__global__ void scatter_kernel(const int* __restrict__ src, const int* __restrict__ tgt,
                               const float* __restrict__ w, int* __restrict__ cursor,
                               int2* __restrict__ edges, int n_edges) {
    int i = blockIdx.x * blockDim.x + threadIdx.x;
    if (i >= n_edges) return;
    int t = tgt[i];
    int pos = atomicAdd(&cursor[t], 1);
    edges[pos] = make_int2(src[i], __float_as_int(w[i]));
}

// --- Per-step kernels --------------------------------------------------------

// Apply previous step's dv (i >= n_tm1, when do_update), Tm1 filter update +
// v[i] = old tm1_v for i < n_tm1. syn is fully overwritten by gather_kernel.
__global__ void neuron_kernel(float* __restrict__ v,
                              const float* __restrict__ syn,
                              float* __restrict__ tm1_f,
                              float* __restrict__ tm1_v,
                              const float* __restrict__ x,
                              const float* __restrict__ tau,
                              const float* __restrict__ vrest,
                              int n_neurons, int n_tm1, int do_update) {
    int i = blockIdx.x * blockDim.x + threadIdx.x;
    if (i >= n_neurons) return;

    if (i < n_tm1) {
        float f  = tm1_f[i];
        float tv = tm1_v[i];
        float xi = x[i];
        float hp = xi - f;
        tm1_f[i] = f + DT * (xi - f) / TAU_HP;
        v[i] = tv;                                // old tm1_v into v before recurrence
        float rect = fmaxf(hp, 0.0f);
        tm1_v[i] = tv + DT * (rect - tv) / TAU_LP;
    } else if (do_update) {
        float vi = v[i];
        float dv = (-vi + syn[i] + vrest[i]) / tau[i];
        v[i] = vi + DT * dv;
    }
}

// CSR-vector gather: 16 lanes per row. Lanes read 16 consecutive int2 (128B)
// per iteration -> coalesced; 4-level shfl_xor reduction within the group.
__global__ void gather_kernel(const int* __restrict__ row_start,
                              const int2* __restrict__ edges,
                              const float* __restrict__ v,
                              float* __restrict__ syn, int n) {
    int tid  = blockIdx.x * blockDim.x + threadIdx.x;
    int row  = tid >> 4;
    int lane = tid & 15;
    if (row >= n) return;
    int s = row_start[row];
    int e = row_start[row + 1];
    float sum = 0.0f;
    for (int j = s + lane; j < e; j += 16) {
        int2 ed = edges[j];
        sum += fmaxf(v[ed.x], 0.0f) * __int_as_float(ed.y);
    }
    sum += __shfl_xor(sum, 8);
    sum += __shfl_xor(sum, 4);
    sum += __shfl_xor(sum, 2);
    sum += __shfl_xor(sum, 1);
    if (lane == 0) syn[row] = sum;
}

// Apply last step's dv and emit final v.
__global__ void final_kernel(const float* __restrict__ v,
                             const float* __restrict__ syn,
                             const float* __restrict__ tau,
                             const float* __restrict__ vrest,
                             float* __restrict__ out,
                             int n_neurons, int n_tm1) {
    int i = blockIdx.x * blockDim.x + threadIdx.x;
    if (i >= n_neurons) return;
    float vi = v[i];
    if (i >= n_tm1) {
        vi = vi + DT * ((-vi + syn[i] + vrest[i]) / tau[i]);
    }
    out[i] = vi;
}

extern "C" void kernel_launch(void* const* d_in, const int* in_sizes, int n_in,
                              void* d_out, int out_size, void* d_ws, size_t ws_size,
                              hipStream_t stream) {
    const float* tm1_input  = (const float*)d_in[0];
    const float* weights    = (const float*)d_in[1];
    const float* tau        = (const float*)d_in[2];
    const float* vrest      = (const float*)d_in[3];
    const int*   source_idx = (const int*)d_in[4];
    const int*   target_idx = (const int*)d_in[5];

    const int n_edges   = in_sizes[1];
    const int n_neurons = in_sizes[2];
    const int n_tm1     = 25000;
    const int steps     = in_sizes[0] / n_tm1;

    size_t off = 0;
    auto alloc_f = [&](size_t n) { size_t o = off; off += n; return o; };
    auto align2  = [&]() { if (off & 1) ++off; };

    float* ws_f = (float*)d_ws;
    int*   ws_i = (int*)d_ws;

    float* v         = ws_f + alloc_f(n_neurons);
    float* syn       = ws_f + alloc_f(n_neurons);
    float* tm1_f     = ws_f + alloc_f(n_tm1);
    float* tm1_v     = ws_f + alloc_f(n_tm1);
    int*   counts    = ws_i + alloc_f(n_neurons);
    int*   row_start = ws_i + alloc_f(n_neurons + 1);
    int*   cursor    = ws_i + alloc_f(n_neurons);
    int*   bsums     = ws_i + alloc_f(SCAN_B);
    align2();
    int2*  edges     = (int2*)(ws_i + alloc_f((size_t)n_edges * 2));
    (void)ws_size;

    float* out = (float*)d_out;

    const int B = 256;
    const int gridN  = (n_neurons + B - 1) / B;
    const int gridN1 = (n_neurons + 1 + B - 1) / B;
    const int gridE  = (n_edges + B - 1) / B;
    const int n_edges4 = n_edges / 4;
    const int gridE4 = (n_edges4 + B - 1) / B;
    const int nScanBlocks = (n_neurons + SCAN_B - 1) / SCAN_B;
    const int gridG  = ((n_neurons * 16) + B - 1) / B;   // 16 lanes per row

    // --- one-time (per launch) CSR build ---
    init_kernel<<<gridN, B, 0, stream>>>(v, tm1_f, tm1_v, counts, n_neurons, n_tm1);
    hist_kernel<<<gridE4, B, 0, stream>>>((const int4*)target_idx, counts, n_edges4);
    scan1_kernel<<<nScanBlocks, SCAN_B, 0, stream>>>(counts, row_start, bsums, n_neurons);
    scan2_kernel<<<1, SCAN_B, 0, stream>>>(bsums, nScanBlocks);
    scan3_kernel<<<gridN1, B, 0, stream>>>(row_start, cursor, bsums, n_neurons, n_edges);
    scatter_kernel<<<gridE, B, 0, stream>>>(source_idx, target_idx, weights, cursor,
                                            edges, n_edges);

    // --- 50 steps, atomic-free ---
    for (int t = 0; t < steps; ++t) {
        neuron_kernel<<<gridN, B, 0, stream>>>(
            v, syn, tm1_f, tm1_v,
            tm1_input + (size_t)t * n_tm1,
            tau, vrest, n_neurons, n_tm1, t > 0 ? 1 : 0);
        gather_kernel<<<gridG, B, 0, stream>>>(row_start, edges, v, syn, n_neurons);
    }

    final_kernel<<<gridN, B, 0, stream>>>(v, syn, tau, vrest, out, n_neurons, n_tm1);
}

// Round 4
// 2149.067 us; speedup vs baseline: 7.5372x; 1.2382x over previous
//
#include <hip/hip_runtime.h>
#include <hip/hip_bf16.h>

#define DT 0.1f
#define TAU_HP 12.3f
#define TAU_LP 2.3f
#define SCAN_B 1024

// Radix-build parameters: bucket = tgt >> BSHIFT (128 targets/bucket).
#define BSHIFT 7
#define BMASK 127
#define BMAX 2048          // max buckets supported (n_neurons <= 262144)
#define CHUNK 16384        // edges per block in hist/bin passes
#define B4_CAP 6144        // max records per bucket in finalize (mean 4096, +32 sigma)

// ---------------------------------------------------------------------------
// R1: atomics removed from steady state via CSR-by-target.
// R2: CSR-vector gather (16 lanes/row, coalesced, shfl reduce).
// R3: build was atomic-fabric-bound (scatter 530us, hist 300us, WRITE 395MB).
//     -> zero-global-atomic radix-by-bucket build:
//        bhist (LDS hist) -> 3-level scan -> bin (LDS cursors) ->
//        finalize (per-bucket LDS hist/scan/rank, in-place, emits row_start).
//     gather: int4 edge loads (2 edges/lane/instr) - vmem-issue bound.
// ---------------------------------------------------------------------------

__global__ void init_kernel(float* __restrict__ v,
                            float* __restrict__ tm1_f,
                            float* __restrict__ tm1_v,
                            int n_neurons, int n_tm1) {
    int i = blockIdx.x * blockDim.x + threadIdx.x;
    if (i < n_neurons) v[i] = 0.0f;
    if (i < n_tm1) { tm1_f[i] = 0.0f; tm1_v[i] = 0.0f; }
}

// --- build pass 1: per-(block,bucket) histogram --------------------------------
__global__ void bhist_kernel(const int* __restrict__ tgt, int* __restrict__ blkhist,
                             int n_edges, int nb, int nblk) {
    __shared__ int hist[BMAX];
    int b = blockIdx.x;
    for (int i = threadIdx.x; i < nb; i += blockDim.x) hist[i] = 0;
    __syncthreads();
    int base = b * CHUNK;
    int end = min(base + CHUNK, n_edges);
    for (int k = base + threadIdx.x; k < end; k += blockDim.x)
        atomicAdd(&hist[tgt[k] >> BSHIFT], 1);
    __syncthreads();
    for (int i = threadIdx.x; i < nb; i += blockDim.x)
        blkhist[(size_t)i * nblk + b] = hist[i];      // bucket-major for scan
}

// --- 3-level exclusive scan (in-place capable: reads in[gid] once) ------------
__global__ void scan1_kernel(const int* in, int* out, int* bsums, int n) {
    __shared__ int s[SCAN_B];
    int gid = blockIdx.x * SCAN_B + threadIdx.x;
    int x = (gid < n) ? in[gid] : 0;
    s[threadIdx.x] = x;
    __syncthreads();
    for (int off = 1; off < SCAN_B; off <<= 1) {
        int t = (threadIdx.x >= off) ? s[threadIdx.x - off] : 0;
        __syncthreads();
        s[threadIdx.x] += t;
        __syncthreads();
    }
    if (gid < n) out[gid] = s[threadIdx.x] - x;       // exclusive
    if (threadIdx.x == SCAN_B - 1) bsums[blockIdx.x] = s[SCAN_B - 1];
}

__global__ void scan2_kernel(int* bsums, int nb) {
    __shared__ int s[SCAN_B];
    int x = (threadIdx.x < nb) ? bsums[threadIdx.x] : 0;
    s[threadIdx.x] = x;
    __syncthreads();
    for (int off = 1; off < SCAN_B; off <<= 1) {
        int t = (threadIdx.x >= off) ? s[threadIdx.x - off] : 0;
        __syncthreads();
        s[threadIdx.x] += t;
        __syncthreads();
    }
    if (threadIdx.x < nb) bsums[threadIdx.x] = s[threadIdx.x] - x;
}

__global__ void scanadd_kernel(int* data, const int* __restrict__ bsums, int n) {
    int gid = blockIdx.x * blockDim.x + threadIdx.x;
    if (gid < n) data[gid] += bsums[gid / SCAN_B];
}

// --- build pass 2: bin edges into bucket order (LDS cursors, no global atomics)
// record = (src | tlow<<18, weight-bits); src < 2^18, tlow 7 bits.
__global__ void bin_kernel(const int* __restrict__ src, const int* __restrict__ tgt,
                           const float* __restrict__ w, const int* __restrict__ scanned,
                           int2* __restrict__ edges, int n_edges, int nb, int nblk) {
    __shared__ int cur[BMAX];
    int b = blockIdx.x;
    for (int i = threadIdx.x; i < nb; i += blockDim.x)
        cur[i] = scanned[(size_t)i * nblk + b];
    __syncthreads();
    int base = b * CHUNK;
    int end = min(base + CHUNK, n_edges);
    for (int k = base + threadIdx.x; k < end; k += blockDim.x) {
        int t = tgt[k];
        int pos = atomicAdd(&cur[t >> BSHIFT], 1);    // LDS atomic
        edges[pos] = make_int2(src[k] | ((t & BMASK) << 18), __float_as_int(w[k]));
    }
}

// --- build pass 3: per-bucket finalize, entirely in LDS, in-place -------------
__global__ void finalize_kernel(int2* edges, const int* __restrict__ scanned,
                                int* __restrict__ row_start,
                                int n_neurons, int n_edges, int nb, int nblk) {
    __shared__ int2 buf[B4_CAP];
    __shared__ int hist[BMASK + 1], ls[BMASK + 1], cur[BMASK + 1];
    int b = blockIdx.x;
    int beg = scanned[(size_t)b * nblk];
    int end = (b == nb - 1) ? n_edges : scanned[(size_t)(b + 1) * nblk];
    int n = min(end - beg, B4_CAP);

    for (int k = threadIdx.x; k < n; k += blockDim.x) buf[k] = edges[beg + k];
    if (threadIdx.x <= BMASK) hist[threadIdx.x] = 0;
    __syncthreads();
    for (int k = threadIdx.x; k < n; k += blockDim.x)
        atomicAdd(&hist[(buf[k].x >> 18) & BMASK], 1);
    __syncthreads();
    if (threadIdx.x <= BMASK) ls[threadIdx.x] = hist[threadIdx.x];
    __syncthreads();
    for (int off = 1; off <= BMASK; off <<= 1) {
        int t = (threadIdx.x <= BMASK && threadIdx.x >= off) ? ls[threadIdx.x - off] : 0;
        __syncthreads();
        if (threadIdx.x <= BMASK) ls[threadIdx.x] += t;   // inclusive
        __syncthreads();
    }
    if (threadIdx.x <= BMASK) {
        int excl = ls[threadIdx.x] - hist[threadIdx.x];
        cur[threadIdx.x] = excl;
        int t = (b << BSHIFT) + threadIdx.x;
        if (t < n_neurons) row_start[t] = beg + excl;
    }
    if (b == nb - 1 && threadIdx.x == 0) row_start[n_neurons] = n_edges;
    __syncthreads();
    for (int k = threadIdx.x; k < n; k += blockDim.x) {
        int2 r = buf[k];
        int pos = atomicAdd(&cur[(r.x >> 18) & BMASK], 1);  // LDS atomic
        edges[beg + pos] = make_int2(r.x & 0x3FFFF, r.y);
    }
}

// --- per-step kernels ---------------------------------------------------------

__global__ void neuron_kernel(float* __restrict__ v,
                              const float* __restrict__ syn,
                              float* __restrict__ tm1_f,
                              float* __restrict__ tm1_v,
                              const float* __restrict__ x,
                              const float* __restrict__ tau,
                              const float* __restrict__ vrest,
                              int n_neurons, int n_tm1, int do_update) {
    int i = blockIdx.x * blockDim.x + threadIdx.x;
    if (i >= n_neurons) return;

    if (i < n_tm1) {
        float f  = tm1_f[i];
        float tv = tm1_v[i];
        float xi = x[i];
        float hp = xi - f;
        tm1_f[i] = f + DT * (xi - f) / TAU_HP;
        v[i] = tv;                                // old tm1_v into v before recurrence
        float rect = fmaxf(hp, 0.0f);
        tm1_v[i] = tv + DT * (rect - tv) / TAU_LP;
    } else if (do_update) {
        float vi = v[i];
        float dv = (-vi + syn[i] + vrest[i]) / tau[i];
        v[i] = vi + DT * dv;
    }
}

// CSR-vector gather: 16 lanes/row, int4 = 2 edges per load (vmem-issue bound).
__global__ void gather_kernel(const int* __restrict__ row_start,
                              const int2* __restrict__ edges,
                              const float* __restrict__ v,
                              float* __restrict__ syn, int n) {
    int tid  = blockIdx.x * blockDim.x + threadIdx.x;
    int row  = tid >> 4;
    int lane = tid & 15;
    if (row >= n) return;
    int s = row_start[row];
    int e = row_start[row + 1];
    float sum = 0.0f;
    for (int p = (s & ~1) + 2 * lane; p < e; p += 32) {
        int4 q = *(const int4*)(edges + p);       // edges base 16B aligned, p even
        if (p >= s)     sum += fmaxf(v[q.x], 0.0f) * __int_as_float(q.y);
        if (p + 1 < e)  sum += fmaxf(v[q.z], 0.0f) * __int_as_float(q.w);
    }
    sum += __shfl_xor(sum, 8);
    sum += __shfl_xor(sum, 4);
    sum += __shfl_xor(sum, 2);
    sum += __shfl_xor(sum, 1);
    if (lane == 0) syn[row] = sum;
}

__global__ void final_kernel(const float* __restrict__ v,
                             const float* __restrict__ syn,
                             const float* __restrict__ tau,
                             const float* __restrict__ vrest,
                             float* __restrict__ out,
                             int n_neurons, int n_tm1) {
    int i = blockIdx.x * blockDim.x + threadIdx.x;
    if (i >= n_neurons) return;
    float vi = v[i];
    if (i >= n_tm1) {
        vi = vi + DT * ((-vi + syn[i] + vrest[i]) / tau[i]);
    }
    out[i] = vi;
}

extern "C" void kernel_launch(void* const* d_in, const int* in_sizes, int n_in,
                              void* d_out, int out_size, void* d_ws, size_t ws_size,
                              hipStream_t stream) {
    const float* tm1_input  = (const float*)d_in[0];
    const float* weights    = (const float*)d_in[1];
    const float* tau        = (const float*)d_in[2];
    const float* vrest      = (const float*)d_in[3];
    const int*   source_idx = (const int*)d_in[4];
    const int*   target_idx = (const int*)d_in[5];

    const int n_edges   = in_sizes[1];
    const int n_neurons = in_sizes[2];
    const int n_tm1     = 25000;
    const int steps     = in_sizes[0] / n_tm1;

    const int nb   = (n_neurons + BMASK) >> BSHIFT;          // 1563 buckets
    const int nblk = (n_edges + CHUNK - 1) / CHUNK;          // 391 blocks
    const int n_scan = nb * nblk;                            // 611,133

    // Workspace (4-byte units). edges first -> 16B aligned for int4 gather.
    size_t off = 0;
    auto alloc = [&](size_t n) { size_t o = off; off += n; return o; };
    int* ws_i = (int*)d_ws;
    float* ws_f = (float*)d_ws;

    int2*  edges     = (int2*)(ws_i + alloc((size_t)(n_edges + 2) * 2));
    float* v         = ws_f + alloc(n_neurons);
    float* syn       = ws_f + alloc(n_neurons);
    float* tm1_f     = ws_f + alloc(n_tm1);
    float* tm1_v     = ws_f + alloc(n_tm1);
    int*   row_start = ws_i + alloc(n_neurons + 1);
    int*   blkhist   = ws_i + alloc((size_t)n_scan);
    int*   bsums     = ws_i + alloc(SCAN_B);
    (void)ws_size;

    float* out = (float*)d_out;

    const int B = 256;
    const int gridN = (n_neurons + B - 1) / B;
    const int gridG = ((n_neurons * 16) + B - 1) / B;
    const int nScanBlocks = (n_scan + SCAN_B - 1) / SCAN_B;  // 597 <= 1024
    const int gridSA = (n_scan + B - 1) / B;

    // --- one-time (per launch) CSR build: zero global atomics ---
    init_kernel<<<gridN, B, 0, stream>>>(v, tm1_f, tm1_v, n_neurons, n_tm1);
    bhist_kernel<<<nblk, 1024, 0, stream>>>(target_idx, blkhist, n_edges, nb, nblk);
    scan1_kernel<<<nScanBlocks, SCAN_B, 0, stream>>>(blkhist, blkhist, bsums, n_scan);
    scan2_kernel<<<1, SCAN_B, 0, stream>>>(bsums, nScanBlocks);
    scanadd_kernel<<<gridSA, B, 0, stream>>>(blkhist, bsums, n_scan);
    bin_kernel<<<nblk, 1024, 0, stream>>>(source_idx, target_idx, weights, blkhist,
                                          edges, n_edges, nb, nblk);
    finalize_kernel<<<nb, 1024, 0, stream>>>(edges, blkhist, row_start,
                                             n_neurons, n_edges, nb, nblk);

    // --- 50 steps, atomic-free ---
    for (int t = 0; t < steps; ++t) {
        neuron_kernel<<<gridN, B, 0, stream>>>(
            v, syn, tm1_f, tm1_v,
            tm1_input + (size_t)t * n_tm1,
            tau, vrest, n_neurons, n_tm1, t > 0 ? 1 : 0);
        gather_kernel<<<gridG, B, 0, stream>>>(row_start, edges, v, syn, n_neurons);
    }

    final_kernel<<<gridN, B, 0, stream>>>(v, syn, tau, vrest, out, n_neurons, n_tm1);
}

// Round 5
// 1836.333 us; speedup vs baseline: 8.8208x; 1.1703x over previous
//
#include <hip/hip_runtime.h>
#include <hip/hip_bf16.h>

#define DT 0.1f
#define TAU_HP 12.3f
#define TAU_LP 2.3f
#define SCAN_B 1024

// Radix-build parameters: bucket = tgt >> BSHIFT (128 targets/bucket).
#define BSHIFT 7
#define BMASK 127
#define BMAX 2048          // max buckets supported (n_neurons <= 262144)
#define CHUNK 32768        // edges per block in hist/bin passes
#define B4_CAP 6144        // max records per bucket in finalize

// ---------------------------------------------------------------------------
// R1: atomics removed from steady state via CSR-by-target.
// R2: CSR-vector gather (16 lanes/row, coalesced, shfl reduce).
// R3: zero-global-atomic radix build (bhist->scan->bin->finalize).
// R4: (a) fused step kernel: gather + integrate + Tm1 filters in ONE kernel
//         via double-buffered v (kernel boundary = the barrier). syn array,
//         neuron_kernel, final_kernel eliminated; 50 launches total.
//     (b) Tm1-target edges dropped at build (dv[:tm1]==0 makes them dead):
//         12.5% less edge traffic everywhere.
//     (c) CHUNK 32768: better bin write bursts.
// ---------------------------------------------------------------------------

__global__ void init_kernel(float* __restrict__ vA,
                            float* __restrict__ tm1_f,
                            int n_neurons, int n_tm1) {
    int i = blockIdx.x * blockDim.x + threadIdx.x;
    if (i < n_neurons) vA[i] = 0.0f;
    if (i < n_tm1) tm1_f[i] = 0.0f;
}

// --- build pass 1: per-(block,bucket) histogram (Tm1 targets dropped) --------
__global__ void bhist_kernel(const int* __restrict__ tgt, int* __restrict__ blkhist,
                             int n_edges, int n_tm1, int nb, int nblk) {
    __shared__ int hist[BMAX];
    int b = blockIdx.x;
    for (int i = threadIdx.x; i < nb; i += blockDim.x) hist[i] = 0;
    __syncthreads();
    int base = b * CHUNK;
    int end = min(base + CHUNK, n_edges);
    for (int k = base + threadIdx.x; k < end; k += blockDim.x) {
        int t = tgt[k];
        if (t >= n_tm1) atomicAdd(&hist[t >> BSHIFT], 1);
    }
    __syncthreads();
    for (int i = threadIdx.x; i < nb; i += blockDim.x)
        blkhist[(size_t)i * nblk + b] = hist[i];      // bucket-major for scan
}

// --- 3-level exclusive scan --------------------------------------------------
__global__ void scan1_kernel(const int* in, int* out, int* bsums, int n) {
    __shared__ int s[SCAN_B];
    int gid = blockIdx.x * SCAN_B + threadIdx.x;
    int x = (gid < n) ? in[gid] : 0;
    s[threadIdx.x] = x;
    __syncthreads();
    for (int off = 1; off < SCAN_B; off <<= 1) {
        int t = (threadIdx.x >= off) ? s[threadIdx.x - off] : 0;
        __syncthreads();
        s[threadIdx.x] += t;
        __syncthreads();
    }
    if (gid < n) out[gid] = s[threadIdx.x] - x;       // exclusive
    if (threadIdx.x == SCAN_B - 1) bsums[blockIdx.x] = s[SCAN_B - 1];
}

__global__ void scan2_kernel(int* bsums, int nb, int* total) {
    __shared__ int s[SCAN_B];
    int x = (threadIdx.x < nb) ? bsums[threadIdx.x] : 0;
    s[threadIdx.x] = x;
    __syncthreads();
    for (int off = 1; off < SCAN_B; off <<= 1) {
        int t = (threadIdx.x >= off) ? s[threadIdx.x - off] : 0;
        __syncthreads();
        s[threadIdx.x] += t;
        __syncthreads();
    }
    if (threadIdx.x == nb - 1) *total = s[threadIdx.x];   // inclusive grand total
    if (threadIdx.x < nb) bsums[threadIdx.x] = s[threadIdx.x] - x;
}

__global__ void scanadd_kernel(int* data, const int* __restrict__ bsums, int n) {
    int gid = blockIdx.x * blockDim.x + threadIdx.x;
    if (gid < n) data[gid] += bsums[gid / SCAN_B];
}

// --- build pass 2: bin kept edges into bucket order (LDS cursors) ------------
// record = (src | tlow<<18, weight-bits); src < 2^18, tlow 7 bits.
__global__ void bin_kernel(const int* __restrict__ src, const int* __restrict__ tgt,
                           const float* __restrict__ w, const int* __restrict__ scanned,
                           int2* __restrict__ edges, int n_edges, int n_tm1,
                           int nb, int nblk) {
    __shared__ int cur[BMAX];
    int b = blockIdx.x;
    for (int i = threadIdx.x; i < nb; i += blockDim.x)
        cur[i] = scanned[(size_t)i * nblk + b];
    __syncthreads();
    int base = b * CHUNK;
    int end = min(base + CHUNK, n_edges);
    for (int k = base + threadIdx.x; k < end; k += blockDim.x) {
        int t = tgt[k];
        if (t < n_tm1) continue;                      // dead edges (dv[:tm1]=0)
        int pos = atomicAdd(&cur[t >> BSHIFT], 1);    // LDS atomic
        edges[pos] = make_int2(src[k] | ((t & BMASK) << 18), __float_as_int(w[k]));
    }
}

// --- build pass 3: per-bucket finalize, entirely in LDS, in-place ------------
__global__ void finalize_kernel(int2* edges, const int* __restrict__ scanned,
                                int* __restrict__ row_start,
                                const int* __restrict__ total,
                                int n_neurons, int nb, int nblk) {
    __shared__ int2 buf[B4_CAP];
    __shared__ int hist[BMASK + 1], ls[BMASK + 1], cur[BMASK + 1];
    int b = blockIdx.x;
    int n_kept = *total;
    int beg = scanned[(size_t)b * nblk];
    int end = (b == nb - 1) ? n_kept : scanned[(size_t)(b + 1) * nblk];
    int n = min(end - beg, B4_CAP);

    for (int k = threadIdx.x; k < n; k += blockDim.x) buf[k] = edges[beg + k];
    if (threadIdx.x <= BMASK) hist[threadIdx.x] = 0;
    __syncthreads();
    for (int k = threadIdx.x; k < n; k += blockDim.x)
        atomicAdd(&hist[(buf[k].x >> 18) & BMASK], 1);
    __syncthreads();
    if (threadIdx.x <= BMASK) ls[threadIdx.x] = hist[threadIdx.x];
    __syncthreads();
    for (int off = 1; off <= BMASK; off <<= 1) {
        int t = (threadIdx.x <= BMASK && threadIdx.x >= off) ? ls[threadIdx.x - off] : 0;
        __syncthreads();
        if (threadIdx.x <= BMASK) ls[threadIdx.x] += t;   // inclusive
        __syncthreads();
    }
    if (threadIdx.x <= BMASK) {
        int excl = ls[threadIdx.x] - hist[threadIdx.x];
        cur[threadIdx.x] = excl;
        int t = (b << BSHIFT) + threadIdx.x;
        if (t < n_neurons) row_start[t] = beg + excl;
    }
    if (b == nb - 1 && threadIdx.x == 0) row_start[n_neurons] = n_kept;
    __syncthreads();
    for (int k = threadIdx.x; k < n; k += blockDim.x) {
        int2 r = buf[k];
        int pos = atomicAdd(&cur[(r.x >> 18) & BMASK], 1);  // LDS atomic
        edges[beg + pos] = make_int2(r.x & 0x3FFFF, r.y);
    }
}

// --- fused per-step kernel ---------------------------------------------------
// Reads vr (state at step k), writes vw (state at step k+1, or out on last).
// 16 lanes per row. Tm1 rows: lane 0 advances HP/LP filters; v-slot carries
// tm1_v (ref writes old tm1_v into v before recurrence; last step copies).
__global__ void step_kernel(const int* __restrict__ row_start,
                            const int2* __restrict__ edges,
                            const float* __restrict__ vr,
                            float* __restrict__ vw,
                            float* __restrict__ tm1_f,
                            const float* __restrict__ x,     // tm1_input + k*n_tm1
                            const float* __restrict__ tau,
                            const float* __restrict__ vrest,
                            int n_neurons, int n_tm1, int last) {
    int tid  = blockIdx.x * blockDim.x + threadIdx.x;
    int row  = tid >> 4;
    int lane = tid & 15;
    if (row >= n_neurons) return;

    if (row < n_tm1) {                       // filter update only; edges dead
        if (lane == 0) {
            float cur = vr[row];             // = tm1_v at step k
            if (last) {
                vw[row] = cur;               // ref: v[:tm1] = old tm1_v
            } else {
                float f  = tm1_f[row];
                float xk = x[row];
                float hp = xk - f;
                tm1_f[row] = f + DT * (xk - f) / TAU_HP;
                vw[row] = cur + DT * (fmaxf(hp, 0.0f) - cur) / TAU_LP;
            }
        }
        return;
    }

    int s = row_start[row];
    int e = row_start[row + 1];
    float sum = 0.0f;
    for (int p = (s & ~1) + 2 * lane; p < e; p += 32) {
        int4 q = *(const int4*)(edges + p);  // 16B aligned (p even)
        if (p >= s)    sum += fmaxf(vr[q.x], 0.0f) * __int_as_float(q.y);
        if (p + 1 < e) sum += fmaxf(vr[q.z], 0.0f) * __int_as_float(q.w);
    }
    sum += __shfl_xor(sum, 8);
    sum += __shfl_xor(sum, 4);
    sum += __shfl_xor(sum, 2);
    sum += __shfl_xor(sum, 1);
    if (lane == 0) {
        float vi = vr[row];
        vw[row] = vi + DT * ((-vi + sum + vrest[row]) / tau[row]);
    }
}

extern "C" void kernel_launch(void* const* d_in, const int* in_sizes, int n_in,
                              void* d_out, int out_size, void* d_ws, size_t ws_size,
                              hipStream_t stream) {
    const float* tm1_input  = (const float*)d_in[0];
    const float* weights    = (const float*)d_in[1];
    const float* tau        = (const float*)d_in[2];
    const float* vrest      = (const float*)d_in[3];
    const int*   source_idx = (const int*)d_in[4];
    const int*   target_idx = (const int*)d_in[5];

    const int n_edges   = in_sizes[1];
    const int n_neurons = in_sizes[2];
    const int n_tm1     = 25000;
    const int steps     = in_sizes[0] / n_tm1;

    const int nb   = (n_neurons + BMASK) >> BSHIFT;          // 1563 buckets
    const int nblk = (n_edges + CHUNK - 1) / CHUNK;          // 196 blocks
    const int n_scan = nb * nblk;                            // 306,348

    // Workspace (4-byte units). edges first -> 16B aligned for int4 gather.
    size_t off = 0;
    auto alloc = [&](size_t n) { size_t o = off; off += n; return o; };
    int* ws_i = (int*)d_ws;
    float* ws_f = (float*)d_ws;

    int2*  edges     = (int2*)(ws_i + alloc((size_t)(n_edges + 2) * 2));
    float* vA        = ws_f + alloc(n_neurons);
    float* vB        = ws_f + alloc(n_neurons);
    float* tm1_f     = ws_f + alloc(n_tm1);
    int*   row_start = ws_i + alloc(n_neurons + 1);
    int*   blkhist   = ws_i + alloc((size_t)n_scan);
    int*   bsums     = ws_i + alloc(SCAN_B);
    int*   total     = ws_i + alloc(1);
    (void)ws_size;

    float* out = (float*)d_out;

    const int B = 256;
    const int gridN = (n_neurons + B - 1) / B;
    const int gridG = ((n_neurons * 16) + B - 1) / B;
    const int nScanBlocks = (n_scan + SCAN_B - 1) / SCAN_B;  // 300 <= 1024
    const int gridSA = (n_scan + B - 1) / B;

    // --- one-time (per launch) CSR build: zero global atomics ---
    init_kernel<<<gridN, B, 0, stream>>>(vA, tm1_f, n_neurons, n_tm1);
    bhist_kernel<<<nblk, 1024, 0, stream>>>(target_idx, blkhist, n_edges, n_tm1,
                                            nb, nblk);
    scan1_kernel<<<nScanBlocks, SCAN_B, 0, stream>>>(blkhist, blkhist, bsums, n_scan);
    scan2_kernel<<<1, SCAN_B, 0, stream>>>(bsums, nScanBlocks, total);
    scanadd_kernel<<<gridSA, B, 0, stream>>>(blkhist, bsums, n_scan);
    bin_kernel<<<nblk, 1024, 0, stream>>>(source_idx, target_idx, weights, blkhist,
                                          edges, n_edges, n_tm1, nb, nblk);
    finalize_kernel<<<nb, 1024, 0, stream>>>(edges, blkhist, row_start, total,
                                             n_neurons, nb, nblk);

    // --- steps: ONE fused kernel per step, double-buffered v ---
    for (int k = 0; k < steps; ++k) {
        const float* vr = (k & 1) ? vB : vA;
        float* vw = (k == steps - 1) ? out : ((k & 1) ? vA : vB);
        step_kernel<<<gridG, B, 0, stream>>>(
            row_start, edges, vr, vw, tm1_f,
            tm1_input + (size_t)k * n_tm1,
            tau, vrest, n_neurons, n_tm1, (k == steps - 1) ? 1 : 0);
    }
}